// Round 1
// baseline (4639.105 us; speedup 1.0000x reference)
//
#include <hip/hip_runtime.h>
#include <stdint.h>

// Problem constants
#define BB   128      // batch
#define LL   128      // latent dim
#define HH   1024     // hidden
#define G4   4096     // 4*H
#define TT   256      // time steps
#define PP   128      // output cols per step

#define NGB  128                 // gate blocks: each owns 8 hidden units (32 weight rows)
#define NFB  8                   // fc blocks: each owns 16 rows of W_fc
#define NB   (NGB + NFB)

typedef _Float16 half8  __attribute__((ext_vector_type(8)));
typedef float   floatx4 __attribute__((ext_vector_type(4)));

__device__ __forceinline__ float sigf(float x) {
  x = fminf(fmaxf(x, -30.f), 30.f);
  return 1.f / (1.f + __expf(-x));
}
__device__ __forceinline__ float tanhf_fast(float x) {
  x = fminf(fmaxf(x, -15.f), 15.f);
  float e = __expf(2.f * x);
  return (e - 1.f) / (e + 1.f);
}
__device__ __forceinline__ unsigned short f2h(float x) {
  _Float16 h = (_Float16)x;
  return __builtin_bit_cast(unsigned short, h);
}

// Monotonic-counter grid barrier (device-scope; cross-XCD safe via __threadfence).
__device__ __forceinline__ void gridbar(unsigned* bar, unsigned target) {
  __syncthreads();
  if (threadIdx.x == 0) {
    __threadfence();                    // release: drain block's writes past L2
    atomicAdd(bar, 1u);                 // device-scope by default
    while (__hip_atomic_load(bar, __ATOMIC_RELAXED, __HIP_MEMORY_SCOPE_AGENT) < target)
      __builtin_amdgcn_s_sleep(2);
    __threadfence();                    // acquire: invalidate stale L1/L2
  }
  __syncthreads();
}

// gates0 = z @ w_ih^T + b_ih + b_hh   (step-0 gates; h0=c0=0, x=0 for t>=1)
__global__ void prep_gates0(const float* __restrict__ z, const float* __restrict__ w_ih,
                            const float* __restrict__ b_ih, const float* __restrict__ b_hh,
                            float* __restrict__ g0) {
  int j = blockIdx.x;     // 0..4095
  int b = threadIdx.x;    // 0..127
  const float* zr = z + b * LL;
  const float* wr = w_ih + (size_t)j * LL;   // uniform across lanes -> broadcast-friendly
  float s = 0.f;
#pragma unroll 4
  for (int k = 0; k < LL; ++k) s += zr[k] * wr[k];
  g0[(size_t)b * G4 + j] = s + b_ih[j] + b_hh[j];
}

// Convert w_hh / W_fc to fp16 in the persistent kernel's LDS layout:
// gate block bid rows: [i0..i7 | g0..g7 | f0..f7 | o0..o7] for units n=bid*8+0..7,
// with each row's 8-elem k-chunks XOR-swizzled by (row&7) to break LDS bank conflicts.
__global__ void prep_weights(const float* __restrict__ w_hh, const float* __restrict__ W_fc,
                             unsigned short* __restrict__ wbuf) {
  int R = blockIdx.x;                 // 0..4223 (4096 gate rows + 128 fc rows)
  const float* src; int rsw;
  if (R < NGB * 32) {
    int bid = R >> 5, r = R & 31, sub = r & 7;
    int g = (r < 8) ? 0 : (r < 16) ? 2 : (r < 24) ? 1 : 3;   // i,g,f,o source blocks
    src = w_hh + (size_t)(g * HH + bid * 8 + sub) * HH;
    rsw = sub;
  } else {
    int p = R - NGB * 32;
    src = W_fc + (size_t)p * HH;
    rsw = p & 7;
  }
  unsigned short* dst = wbuf + (size_t)R * HH;
  for (int k = threadIdx.x; k < HH; k += blockDim.x) {
    int dk = (((k >> 3) ^ rsw) << 3) | (k & 7);
    _Float16 v = (_Float16)src[k];
    dst[dk] = __builtin_bit_cast(unsigned short, v);
  }
}

// One K=1024 MFMA pass: C[2 mtiles x NT ntiles], A streamed from global h (fp16),
// B from LDS (fp16, swizzled). 8-deep A prefetch to hide L2 latency at 1 wave/SIMD.
template <int NT>
__device__ __forceinline__ void gemm2xNT(const half8* __restrict__ hb8,
                                         const half8* __restrict__ w8,
                                         int abase0, int abase1,
                                         int quad, int rsw, int l15,
                                         floatx4 acc[2][NT]) {
  half8 ap0[8], ap1[8];
#pragma unroll
  for (int i = 0; i < 8; ++i) { ap0[i] = hb8[abase0 + i * 4]; ap1[i] = hb8[abase1 + i * 4]; }
#pragma unroll
  for (int kc = 0; kc < 32; ++kc) {
    half8 a0 = ap0[kc & 7], a1 = ap1[kc & 7];
    if (kc < 24) {
      ap0[kc & 7] = hb8[abase0 + (kc + 8) * 4];
      ap1[kc & 7] = hb8[abase1 + (kc + 8) * 4];
    }
    int sw = (kc * 4 + quad) ^ rsw;
#pragma unroll
    for (int nt = 0; nt < NT; ++nt) {
      half8 b = w8[(nt * 16 + l15) * 128 + sw];
      acc[0][nt] = __builtin_amdgcn_mfma_f32_16x16x32_f16(a0, b, acc[0][nt], 0, 0, 0);
      acc[1][nt] = __builtin_amdgcn_mfma_f32_16x16x32_f16(a1, b, acc[1][nt], 0, 0, 0);
    }
  }
}

__global__ __launch_bounds__(256, 1) void lstm_persist(
    const float* __restrict__ g0,
    const unsigned short* __restrict__ wbuf,
    const float* __restrict__ b_ih, const float* __restrict__ b_hh,
    const float* __restrict__ b_fc,
    float* __restrict__ out,
    unsigned short* __restrict__ hbuf,   // [2][B][H] fp16 double buffer
    unsigned* __restrict__ bar) {
  __shared__ __align__(16) unsigned short sW[32 * HH];   // 64 KiB
  const int tid  = threadIdx.x;
  const int wv   = tid >> 6;
  const int lane = tid & 63;
  const int quad = lane >> 4;
  const int l15  = lane & 15;
  const int bid  = blockIdx.x;
  const bool isg = bid < NGB;
  const int rsw  = l15 & 7;

  { // stage this block's weight slice into LDS (already fp16 + swizzled in wbuf)
    const uint4* s4 = (const uint4*)(wbuf +
        (size_t)(isg ? bid * 32 : NGB * 32 + (bid - NGB) * 16) * HH);
    uint4* d4 = (uint4*)sW;
    const int n16 = (isg ? 32 * HH : 16 * HH) / 8;
    for (int i = tid; i < n16; i += 256) d4[i] = s4[i];
  }
  __syncthreads();
  const half8* w8 = (const half8*)sW;
  const floatx4 z4 = {0.f, 0.f, 0.f, 0.f};

  if (isg) {
    const int n = bid * 8 + rsw;   // hidden unit this lane touches
    float bias0, bias1;
    if (l15 < 8) { bias0 = b_ih[n]          + b_hh[n];              // i
                   bias1 = b_ih[HH + n]     + b_hh[HH + n]; }       // f
    else         { bias0 = b_ih[2*HH + n]   + b_hh[2*HH + n];       // g
                   bias1 = b_ih[3*HH + n]   + b_hh[3*HH + n]; }     // o
    float c[2][4] = {{0,0,0,0},{0,0,0,0}};

    // ---- t = 0: gates precomputed in g0; c_prev = 0
    if (l15 < 8) {
#pragma unroll
      for (int mt = 0; mt < 2; ++mt)
#pragma unroll
        for (int r = 0; r < 4; ++r) {
          const int m = wv * 32 + mt * 16 + quad * 4 + r;
          const float* gr = g0 + (size_t)m * G4;
          float iv = gr[n], gv = gr[2 * HH + n], ov = gr[3 * HH + n];
          float ct = sigf(iv) * tanhf_fast(gv);
          c[mt][r] = ct;
          hbuf[(size_t)m * HH + n] = f2h(sigf(ov) * tanhf_fast(ct));
        }
    }
    gridbar(bar, NB);

    const int abase0 = (wv * 32 +      l15) * 128 + quad;
    const int abase1 = (wv * 32 + 16 + l15) * 128 + quad;

    for (int t = 1; t < TT; ++t) {
      const half8* hb8 = (const half8*)(hbuf + (size_t)((t - 1) & 1) * BB * HH);
      unsigned short* hw = hbuf + (size_t)(t & 1) * BB * HH;
      floatx4 acc[2][2] = {{z4, z4}, {z4, z4}};
      gemm2xNT<2>(hb8, w8, abase0, abase1, quad, rsw, l15, acc);
#pragma unroll
      for (int mt = 0; mt < 2; ++mt)
#pragma unroll
        for (int r = 0; r < 4; ++r) {
          float v0 = acc[mt][0][r] + bias0;   // lane<8: i_n   lane>=8: g_n
          float v1 = acc[mt][1][r] + bias1;   // lane<8: f_n   lane>=8: o_n
          float gv = __shfl_xor(v0, 8);
          float ov = __shfl_xor(v1, 8);
          if (l15 < 8) {
            float ct = sigf(v1) * c[mt][r] + sigf(v0) * tanhf_fast(gv);
            c[mt][r] = ct;
            const int m = wv * 32 + mt * 16 + quad * 4 + r;
            hw[(size_t)m * HH + n] = f2h(sigf(ov) * tanhf_fast(ct));
          }
        }
      gridbar(bar, (unsigned)NB * (unsigned)(t + 1));
    }
  } else {
    // fc block: y_{t-1} = h_{t-1} @ W_fc^T + b_fc, overlapped with step-t gate GEMMs
    const int fb = bid - NGB;
    const int pcol = fb * 16 + l15;
    const float biasf = b_fc[pcol];
    const int abase0 = ((wv * 2 + 0) * 16 + l15) * 128 + quad;
    const int abase1 = ((wv * 2 + 1) * 16 + l15) * 128 + quad;

    gridbar(bar, NB);   // t = 0: nothing to project yet

    for (int t = 1; t <= TT; ++t) {
      const half8* hb8 = (const half8*)(hbuf + (size_t)((t - 1) & 1) * BB * HH);
      floatx4 acc[2][1] = {{z4}, {z4}};
      gemm2xNT<1>(hb8, w8, abase0, abase1, quad, rsw, l15, acc);
#pragma unroll
      for (int mt = 0; mt < 2; ++mt)
#pragma unroll
        for (int r = 0; r < 4; ++r) {
          const int m = (wv * 2 + mt) * 16 + quad * 4 + r;
          out[(size_t)m * (TT * PP) + (size_t)(t - 1) * PP + pcol] = acc[mt][0][r] + biasf;
        }
      if (t < TT) gridbar(bar, (unsigned)NB * (unsigned)(t + 1));
    }
  }
}

extern "C" void kernel_launch(void* const* d_in, const int* in_sizes, int n_in,
                              void* d_out, int out_size, void* d_ws, size_t ws_size,
                              hipStream_t stream) {
  const float* z    = (const float*)d_in[1];
  const float* w_ih = (const float*)d_in[2];
  const float* w_hh = (const float*)d_in[3];
  const float* b_ih = (const float*)d_in[4];
  const float* b_hh = (const float*)d_in[5];
  const float* W_fc = (const float*)d_in[6];
  const float* b_fc = (const float*)d_in[7];
  float* out = (float*)d_out;

  // workspace layout (~10.8 MiB total)
  char* ws = (char*)d_ws;
  unsigned*       bar  = (unsigned*)ws;                                        // 64 B
  unsigned short* hbuf = (unsigned short*)(ws + 4096);                         // 512 KiB
  float*          g0   = (float*)(ws + 4096 + (size_t)2 * BB * HH * 2);        // 2 MiB
  unsigned short* wbuf = (unsigned short*)(ws + 4096 + (size_t)2 * BB * HH * 2
                                              + (size_t)BB * G4 * 4);          // 8.25 MiB

  hipMemsetAsync(bar, 0, 64, stream);
  prep_gates0 <<<dim3(G4), dim3(BB), 0, stream>>>(z, w_ih, b_ih, b_hh, g0);
  prep_weights<<<dim3(NGB * 32 + NFB * 16), dim3(256), 0, stream>>>(w_hh, W_fc, wbuf);
  lstm_persist<<<dim3(NB), dim3(256), 0, stream>>>(g0, wbuf, b_ih, b_hh, b_fc,
                                                   out, hbuf, bar);
}

// Round 2
// 3770.509 us; speedup vs baseline: 1.2304x; 1.2304x over previous
//
#include <hip/hip_runtime.h>
#include <stdint.h>

// Problem constants
#define BB   128      // batch
#define LL   128      // latent dim
#define HH   1024     // hidden
#define G4   4096     // 4*H
#define TT   256      // time steps
#define PP   128      // output cols per step

#define NGB  64                  // gate blocks: each owns 16 hidden units (64 weight rows)
#define NFB  8                   // fc blocks: each owns 16 rows of W_fc
#define NB   (NGB + NFB)

typedef _Float16 half8  __attribute__((ext_vector_type(8)));
typedef float   floatx4 __attribute__((ext_vector_type(4)));

__device__ __forceinline__ float sigf(float x) {
  x = fminf(fmaxf(x, -30.f), 30.f);
  return 1.f / (1.f + __expf(-x));
}
__device__ __forceinline__ float tanhf_fast(float x) {
  x = fminf(fmaxf(x, -15.f), 15.f);
  float e = __expf(2.f * x);
  return (e - 1.f) / (e + 1.f);
}
__device__ __forceinline__ unsigned short f2h(float x) {
  _Float16 h = (_Float16)x;
  return __builtin_bit_cast(unsigned short, h);
}

// Monotonic-counter grid barrier (device-scope; cross-XCD safe via __threadfence).
__device__ __forceinline__ void gridbar(unsigned* bar, unsigned target) {
  __syncthreads();
  if (threadIdx.x == 0) {
    __threadfence();                    // release: push h-writes to LLC
    atomicAdd(bar, 1u);
    while (__hip_atomic_load(bar, __ATOMIC_RELAXED, __HIP_MEMORY_SCOPE_AGENT) < target)
      __builtin_amdgcn_s_sleep(2);
    __threadfence();                    // acquire: inv L1/L2 so h reads are fresh
  }
  __syncthreads();
}

// gates0 = z @ w_ih^T + b_ih + b_hh   (step-0 gates; h0=c0=0, x=0 for t>=1)
__global__ void prep_gates0(const float* __restrict__ z, const float* __restrict__ w_ih,
                            const float* __restrict__ b_ih, const float* __restrict__ b_hh,
                            float* __restrict__ g0) {
  int j = blockIdx.x;     // 0..4095
  int b = threadIdx.x;    // 0..127
  const float* zr = z + b * LL;
  const float* wr = w_ih + (size_t)j * LL;
  float s = 0.f;
#pragma unroll 4
  for (int k = 0; k < LL; ++k) s += zr[k] * wr[k];
  g0[(size_t)b * G4 + j] = s + b_ih[j] + b_hh[j];
}

// Convert w_hh / W_fc to fp16 in the persistent kernel's LDS layout.
// Gate block bid owns units u = bid*16 .. bid*16+15; LDS rows (tile*16+nl) for
// tile 0..3 = gates i,g,f,o of unit nl. Each row's 8-elem k-chunks are
// XOR-swizzled by (nl&7) so the wave's B-reads are same-bank-free.
__global__ void prep_weights(const float* __restrict__ w_hh, const float* __restrict__ W_fc,
                             unsigned short* __restrict__ wbuf) {
  int R = blockIdx.x;                 // 0..4223 (4096 gate rows + 128 fc rows)
  const float* src; int rsw;
  if (R < NGB * 64) {
    int bid = R >> 6, rr = R & 63, tile = rr >> 4, nl = rr & 15;
    int g = (tile == 0) ? 0 : (tile == 1) ? 2 : (tile == 2) ? 1 : 3;  // i,g,f,o
    src = w_hh + (size_t)(g * HH + bid * 16 + nl) * HH;
    rsw = nl & 7;
  } else {
    int p = R - NGB * 64;
    src = W_fc + (size_t)p * HH;
    rsw = p & 7;
  }
  unsigned short* dst = wbuf + (size_t)R * HH;
  for (int k = threadIdx.x; k < HH; k += blockDim.x) {
    int dk = (((k >> 3) ^ rsw) << 3) | (k & 7);
    _Float16 v = (_Float16)src[k];
    dst[dk] = __builtin_bit_cast(unsigned short, v);
  }
}

// One K=1024 MFMA pass: C[2 mtiles x NT ntiles], A streamed from global h (fp16),
// B from LDS (fp16, swizzled). 8-deep A prefetch per m-stream to hide LLC latency.
template <int NT>
__device__ __forceinline__ void gemm2xNT(const half8* __restrict__ hb8,
                                         const half8* __restrict__ w8,
                                         int abase0, int abase1,
                                         int quad, int rsw, int l15,
                                         floatx4 acc[2][NT]) {
  half8 ap0[8], ap1[8];
#pragma unroll
  for (int i = 0; i < 8; ++i) { ap0[i] = hb8[abase0 + i * 4]; ap1[i] = hb8[abase1 + i * 4]; }
#pragma unroll
  for (int kc = 0; kc < 32; ++kc) {
    half8 a0 = ap0[kc & 7], a1 = ap1[kc & 7];
    if (kc < 24) {
      ap0[kc & 7] = hb8[abase0 + (kc + 8) * 4];
      ap1[kc & 7] = hb8[abase1 + (kc + 8) * 4];
    }
    int sw = (kc * 4 + quad) ^ rsw;
#pragma unroll
    for (int nt = 0; nt < NT; ++nt) {
      half8 b = w8[(nt * 16 + l15) * 128 + sw];
      acc[0][nt] = __builtin_amdgcn_mfma_f32_16x16x32_f16(a0, b, acc[0][nt], 0, 0, 0);
      acc[1][nt] = __builtin_amdgcn_mfma_f32_16x16x32_f16(a1, b, acc[1][nt], 0, 0, 0);
    }
  }
}

__global__ __launch_bounds__(256, 1) void lstm_persist(
    const float* __restrict__ g0,
    const unsigned short* __restrict__ wbuf,
    const float* __restrict__ b_ih, const float* __restrict__ b_hh,
    const float* __restrict__ b_fc,
    float* __restrict__ out,
    unsigned short* __restrict__ hbuf,   // [2][B][H] fp16 double buffer
    unsigned* __restrict__ bar) {
  extern __shared__ __align__(16) unsigned short sW[];   // 128 KiB (gate) / 32 KiB used (fc)
  const int tid  = threadIdx.x;
  const int wv   = tid >> 6;
  const int lane = tid & 63;
  const int quad = lane >> 4;
  const int l15  = lane & 15;
  const int bid  = blockIdx.x;
  const bool isg = bid < NGB;
  const int rsw  = l15 & 7;

  { // stage this block's weight slice into LDS (already fp16 + swizzled in wbuf)
    const uint4* s4 = (const uint4*)(wbuf +
        (size_t)(isg ? bid * 64 : NGB * 64 + (bid - NGB) * 16) * HH);
    uint4* d4 = (uint4*)sW;
    const int n16 = (isg ? 64 * HH : 16 * HH) / 8;
    for (int i = tid; i < n16; i += 256) d4[i] = s4[i];
  }
  __syncthreads();
  const half8* w8 = (const half8*)sW;
  const floatx4 z4 = {0.f, 0.f, 0.f, 0.f};

  if (isg) {
    const int u = bid * 16 + l15;   // hidden unit this lane owns (all 4 gates)
    const float bi = b_ih[u]          + b_hh[u];
    const float bf = b_ih[HH + u]     + b_hh[HH + u];
    const float bg = b_ih[2*HH + u]   + b_hh[2*HH + u];
    const float bo = b_ih[3*HH + u]   + b_hh[3*HH + u];
    float c[2][4] = {{0,0,0,0},{0,0,0,0}};

    // ---- t = 0: gates precomputed in g0; c_prev = 0
#pragma unroll
    for (int mt = 0; mt < 2; ++mt)
#pragma unroll
      for (int r = 0; r < 4; ++r) {
        const int m = wv * 32 + mt * 16 + quad * 4 + r;
        const float* gr = g0 + (size_t)m * G4;
        float iv = gr[u], gv = gr[2 * HH + u], ov = gr[3 * HH + u];
        float ct = sigf(iv) * tanhf_fast(gv);
        c[mt][r] = ct;
        hbuf[(size_t)m * HH + u] = f2h(sigf(ov) * tanhf_fast(ct));
      }
    gridbar(bar, NB);

    const int abase0 = (wv * 32 +      l15) * 128 + quad;
    const int abase1 = (wv * 32 + 16 + l15) * 128 + quad;

    for (int t = 1; t < TT; ++t) {
      const half8* hb8 = (const half8*)(hbuf + (size_t)((t - 1) & 1) * BB * HH);
      unsigned short* hw = hbuf + (size_t)(t & 1) * BB * HH;
      floatx4 acc[2][4] = {{z4, z4, z4, z4}, {z4, z4, z4, z4}};
      gemm2xNT<4>(hb8, w8, abase0, abase1, quad, rsw, l15, acc);
#pragma unroll
      for (int mt = 0; mt < 2; ++mt)
#pragma unroll
        for (int r = 0; r < 4; ++r) {
          float iv = sigf(acc[mt][0][r] + bi);
          float gv = tanhf_fast(acc[mt][1][r] + bg);
          float fv = sigf(acc[mt][2][r] + bf);
          float ov = sigf(acc[mt][3][r] + bo);
          float ct = fv * c[mt][r] + iv * gv;
          c[mt][r] = ct;
          const int m = wv * 32 + mt * 16 + quad * 4 + r;
          hw[(size_t)m * HH + u] = f2h(ov * tanhf_fast(ct));
        }
      gridbar(bar, (unsigned)NB * (unsigned)(t + 1));
    }
  } else {
    // fc block: y_{t-1} = h_{t-1} @ W_fc^T + b_fc, overlapped with step-t gate GEMMs
    const int fb = bid - NGB;
    const int pcol = fb * 16 + l15;
    const float biasf = b_fc[pcol];
    const int abase0 = ((wv * 2 + 0) * 16 + l15) * 128 + quad;
    const int abase1 = ((wv * 2 + 1) * 16 + l15) * 128 + quad;

    gridbar(bar, NB);   // t = 0: nothing to project yet

    for (int t = 1; t <= TT; ++t) {
      const half8* hb8 = (const half8*)(hbuf + (size_t)((t - 1) & 1) * BB * HH);
      floatx4 acc[2][1] = {{z4}, {z4}};
      gemm2xNT<1>(hb8, w8, abase0, abase1, quad, rsw, l15, acc);
#pragma unroll
      for (int mt = 0; mt < 2; ++mt)
#pragma unroll
        for (int r = 0; r < 4; ++r) {
          const int m = (wv * 2 + mt) * 16 + quad * 4 + r;
          out[(size_t)m * (TT * PP) + (size_t)(t - 1) * PP + pcol] = acc[mt][0][r] + biasf;
        }
      if (t < TT) gridbar(bar, (unsigned)NB * (unsigned)(t + 1));
    }
  }
}

extern "C" void kernel_launch(void* const* d_in, const int* in_sizes, int n_in,
                              void* d_out, int out_size, void* d_ws, size_t ws_size,
                              hipStream_t stream) {
  const float* z    = (const float*)d_in[1];
  const float* w_ih = (const float*)d_in[2];
  const float* w_hh = (const float*)d_in[3];
  const float* b_ih = (const float*)d_in[4];
  const float* b_hh = (const float*)d_in[5];
  const float* W_fc = (const float*)d_in[6];
  const float* b_fc = (const float*)d_in[7];
  float* out = (float*)d_out;

  // workspace layout (~10.8 MiB total)
  char* ws = (char*)d_ws;
  unsigned*       bar  = (unsigned*)ws;                                        // 64 B
  unsigned short* hbuf = (unsigned short*)(ws + 4096);                         // 512 KiB
  float*          g0   = (float*)(ws + 4096 + (size_t)2 * BB * HH * 2);        // 2 MiB
  unsigned short* wbuf = (unsigned short*)(ws + 4096 + (size_t)2 * BB * HH * 2
                                              + (size_t)BB * G4 * 4);          // 8.25 MiB

  // allow 128 KiB dynamic LDS (gfx950 has 160 KiB/CU)
  (void)hipFuncSetAttribute(reinterpret_cast<const void*>(lstm_persist),
                            hipFuncAttributeMaxDynamicSharedMemorySize, 160 * 1024);

  hipMemsetAsync(bar, 0, 64, stream);
  prep_gates0 <<<dim3(G4), dim3(BB), 0, stream>>>(z, w_ih, b_ih, b_hh, g0);
  prep_weights<<<dim3(NGB * 64 + NFB * 16), dim3(256), 0, stream>>>(w_hh, W_fc, wbuf);
  lstm_persist<<<dim3(NB), dim3(256), 128 * 1024, stream>>>(g0, wbuf, b_ih, b_hh, b_fc,
                                                            out, hbuf, bar);
}

// Round 3
// 3188.029 us; speedup vs baseline: 1.4552x; 1.1827x over previous
//
#include <hip/hip_runtime.h>
#include <stdint.h>

// Problem constants
#define BB   128      // batch
#define LL   128      // latent dim
#define HH   1024     // hidden
#define G4   4096     // 4*H
#define TT   256      // time steps
#define PP   128      // output cols per step

#define NGB  64                  // gate blocks: each owns 16 hidden units (64 weight rows)
#define NFB  8                   // fc blocks: each owns 16 rows of W_fc
#define NB   (NGB + NFB)

// HW_REG_XCC_ID = hwreg id 20, offset 0, size 32 -> imm = 20 | (0<<6) | (31<<11)
#define XCC_HWREG 63508

typedef _Float16 half8  __attribute__((ext_vector_type(8)));
typedef float   floatx4 __attribute__((ext_vector_type(4)));

__device__ __forceinline__ float sigf(float x) {
  x = fminf(fmaxf(x, -30.f), 30.f);
  return 1.f / (1.f + __expf(-x));
}
__device__ __forceinline__ float tanhf_fast(float x) {
  x = fminf(fmaxf(x, -15.f), 15.f);
  float e = __expf(2.f * x);
  return (e - 1.f) / (e + 1.f);
}
__device__ __forceinline__ unsigned short f2h(float x) {
  _Float16 h = (_Float16)x;
  return __builtin_bit_cast(unsigned short, h);
}
// agent-scope write-through h store: visible at LLC once vmcnt(0) drains
__device__ __forceinline__ void store_h(unsigned short* p, float x) {
  __hip_atomic_store(p, f2h(x), __ATOMIC_RELAXED, __HIP_MEMORY_SCOPE_AGENT);
}

// Flat monotonic grid barrier with full fences (used ONCE, after census + t=0).
__device__ __forceinline__ void gridbar_flat(unsigned* bar, unsigned target) {
  __syncthreads();
  if (threadIdx.x == 0) {
    __threadfence();
    atomicAdd(bar, 1u);
    while (__hip_atomic_load(bar, __ATOMIC_RELAXED, __HIP_MEMORY_SCOPE_AGENT) < target)
      __builtin_amdgcn_s_sleep(1);
    __threadfence();
  }
  __syncthreads();
}

// gates0 = z @ w_ih^T + b_ih + b_hh   (step-0 gates; h0=c0=0, x=0 for t>=1)
__global__ void prep_gates0(const float* __restrict__ z, const float* __restrict__ w_ih,
                            const float* __restrict__ b_ih, const float* __restrict__ b_hh,
                            float* __restrict__ g0) {
  int j = blockIdx.x;     // 0..4095
  int b = threadIdx.x;    // 0..127
  const float* zr = z + b * LL;
  const float* wr = w_ih + (size_t)j * LL;
  float s = 0.f;
#pragma unroll 4
  for (int k = 0; k < LL; ++k) s += zr[k] * wr[k];
  g0[(size_t)b * G4 + j] = s + b_ih[j] + b_hh[j];
}

// Convert w_hh / W_fc to fp16 in the persistent kernel's LDS layout.
// Gate block bid owns units u = bid*16 .. bid*16+15; LDS rows (tile*16+nl) for
// tile 0..3 = gates i,g,f,o of unit nl. Each row's 8-elem k-chunks are
// XOR-swizzled by (nl&7) so the wave's B-reads are same-bank-free.
__global__ void prep_weights(const float* __restrict__ w_hh, const float* __restrict__ W_fc,
                             unsigned short* __restrict__ wbuf) {
  int R = blockIdx.x;                 // 0..4223 (4096 gate rows + 128 fc rows)
  const float* src; int rsw;
  if (R < NGB * 64) {
    int bid = R >> 6, rr = R & 63, tile = rr >> 4, nl = rr & 15;
    int g = (tile == 0) ? 0 : (tile == 1) ? 2 : (tile == 2) ? 1 : 3;  // i,g,f,o
    src = w_hh + (size_t)(g * HH + bid * 16 + nl) * HH;
    rsw = nl & 7;
  } else {
    int p = R - NGB * 64;
    src = W_fc + (size_t)p * HH;
    rsw = p & 7;
  }
  unsigned short* dst = wbuf + (size_t)R * HH;
  for (int k = threadIdx.x; k < HH; k += blockDim.x) {
    int dk = (((k >> 3) ^ rsw) << 3) | (k & 7);
    _Float16 v = (_Float16)src[k];
    dst[dk] = __builtin_bit_cast(unsigned short, v);
  }
}

// One K=1024 MFMA pass: C[2 mtiles x NT ntiles], A streamed from global h (fp16),
// B from LDS (fp16, swizzled). 8-deep A prefetch per m-stream to hide latency.
template <int NT>
__device__ __forceinline__ void gemm2xNT(const half8* __restrict__ hb8,
                                         const half8* __restrict__ w8,
                                         int abase0, int abase1,
                                         int quad, int rsw, int l15,
                                         floatx4 acc[2][NT]) {
  half8 ap0[8], ap1[8];
#pragma unroll
  for (int i = 0; i < 8; ++i) { ap0[i] = hb8[abase0 + i * 4]; ap1[i] = hb8[abase1 + i * 4]; }
#pragma unroll
  for (int kc = 0; kc < 32; ++kc) {
    half8 a0 = ap0[kc & 7], a1 = ap1[kc & 7];
    if (kc < 24) {
      ap0[kc & 7] = hb8[abase0 + (kc + 8) * 4];
      ap1[kc & 7] = hb8[abase1 + (kc + 8) * 4];
    }
    int sw = (kc * 4 + quad) ^ rsw;
#pragma unroll
    for (int nt = 0; nt < NT; ++nt) {
      half8 b = w8[(nt * 16 + l15) * 128 + sw];
      acc[0][nt] = __builtin_amdgcn_mfma_f32_16x16x32_f16(a0, b, acc[0][nt], 0, 0, 0);
      acc[1][nt] = __builtin_amdgcn_mfma_f32_16x16x32_f16(a1, b, acc[1][nt], 0, 0, 0);
    }
  }
}

// Hierarchical per-step barrier. lbar = this XCD's arrival line, gbar = global.
// s = 1-based step index; counters are monotonic (no reset).
__device__ __forceinline__ void stepbar(unsigned* lbar, unsigned* gbar,
                                        unsigned lcnt, unsigned nldr, bool leader,
                                        unsigned s) {
  __syncthreads();
  if (threadIdx.x == 0) {
    asm volatile("s_waitcnt vmcnt(0)" ::: "memory");   // h stores (write-through) done
    __hip_atomic_fetch_add(lbar, 1u, __ATOMIC_RELAXED, __HIP_MEMORY_SCOPE_AGENT);
    if (leader) {
      while (__hip_atomic_load(lbar, __ATOMIC_RELAXED, __HIP_MEMORY_SCOPE_AGENT) < lcnt * s)
        __builtin_amdgcn_s_sleep(1);
      // ONE L2 writeback walk per XCD per step (covers all locals' dirty lines)
      __builtin_amdgcn_fence(__ATOMIC_RELEASE, "agent");
      __hip_atomic_fetch_add(gbar, 1u, __ATOMIC_RELAXED, __HIP_MEMORY_SCOPE_AGENT);
    }
    while (__hip_atomic_load(gbar, __ATOMIC_RELAXED, __HIP_MEMORY_SCOPE_AGENT) < nldr * s)
      __builtin_amdgcn_s_sleep(1);
    __builtin_amdgcn_fence(__ATOMIC_ACQUIRE, "agent");  // inv L1/L2 (cheap flash inv)
  }
  __syncthreads();
}

__global__ __launch_bounds__(256, 1) void lstm_persist(
    const float* __restrict__ g0,
    const unsigned short* __restrict__ wbuf,
    const float* __restrict__ b_ih, const float* __restrict__ b_hh,
    const float* __restrict__ b_fc,
    float* __restrict__ out,
    unsigned short* __restrict__ hbuf,   // [2][B][H] fp16 double buffer
    unsigned* __restrict__ ctl) {        // census[8] | flat | gbar | lbar[8] (padded lines)
  extern __shared__ __align__(16) unsigned short sW[];
  const int tid  = threadIdx.x;
  const int wv   = tid >> 6;
  const int lane = tid & 63;
  const int quad = lane >> 4;
  const int l15  = lane & 15;
  const int bid  = blockIdx.x;
  const bool isg = bid < NGB;
  const int rsw  = l15 & 7;

  unsigned* census = ctl;            // 8 uints (one line)
  unsigned* fbar   = ctl + 32;       // flat barrier counter
  unsigned* gbar   = ctl + 64;       // global step counter
  // per-XCD lines at ctl + 128 + x*32 (128 B apart)

  // census: which physical XCD am I on, and am I its leader?
  unsigned myx = 0, rank = 0;
  if (tid == 0) {
    myx  = __builtin_amdgcn_s_getreg(XCC_HWREG) & 7u;
    rank = atomicAdd(&census[myx], 1u);
  }

  { // stage this block's weight slice into LDS (already fp16 + swizzled in wbuf)
    const uint4* s4 = (const uint4*)(wbuf +
        (size_t)(isg ? bid * 64 : NGB * 64 + (bid - NGB) * 16) * HH);
    uint4* d4 = (uint4*)sW;
    const int n16 = (isg ? 64 * HH : 16 * HH) / 8;
    for (int i = tid; i < n16; i += 256) d4[i] = s4[i];
  }
  __syncthreads();
  const half8* w8 = (const half8*)sW;
  const floatx4 z4 = {0.f, 0.f, 0.f, 0.f};

  if (isg) {
    const int u = bid * 16 + l15;   // hidden unit this lane owns (all 4 gates)
    const float bi = b_ih[u]          + b_hh[u];
    const float bf = b_ih[HH + u]     + b_hh[HH + u];
    const float bg = b_ih[2*HH + u]   + b_hh[2*HH + u];
    const float bo = b_ih[3*HH + u]   + b_hh[3*HH + u];
    float c[2][4] = {{0,0,0,0},{0,0,0,0}};

    // ---- t = 0: gates precomputed in g0; c_prev = 0
#pragma unroll
    for (int mt = 0; mt < 2; ++mt)
#pragma unroll
      for (int r = 0; r < 4; ++r) {
        const int m = wv * 32 + mt * 16 + quad * 4 + r;
        const float* gr = g0 + (size_t)m * G4;
        float iv = gr[u], gv = gr[2 * HH + u], ov = gr[3 * HH + u];
        float ct = sigf(iv) * tanhf_fast(gv);
        c[mt][r] = ct;
        store_h(hbuf + (size_t)m * HH + u, sigf(ov) * tanhf_fast(ct));
      }
    gridbar_flat(fbar, NB);   // also publishes census

    unsigned lcnt = 0, nldr = 0; unsigned* lbar = nullptr; bool leader = false;
    if (tid == 0) {
      lcnt = __hip_atomic_load(&census[myx], __ATOMIC_RELAXED, __HIP_MEMORY_SCOPE_AGENT);
      for (int i = 0; i < 8; ++i)
        nldr += (__hip_atomic_load(&census[i], __ATOMIC_RELAXED, __HIP_MEMORY_SCOPE_AGENT) > 0);
      lbar = ctl + 128 + myx * 32;
      leader = (rank == 0);
    }

    const int abase0 = (wv * 32 +      l15) * 128 + quad;
    const int abase1 = (wv * 32 + 16 + l15) * 128 + quad;

    for (int t = 1; t < TT; ++t) {
      const half8* hb8 = (const half8*)(hbuf + (size_t)((t - 1) & 1) * BB * HH);
      unsigned short* hw = hbuf + (size_t)(t & 1) * BB * HH;
      floatx4 acc[2][4] = {{z4, z4, z4, z4}, {z4, z4, z4, z4}};
      gemm2xNT<4>(hb8, w8, abase0, abase1, quad, rsw, l15, acc);
#pragma unroll
      for (int mt = 0; mt < 2; ++mt)
#pragma unroll
        for (int r = 0; r < 4; ++r) {
          float iv = sigf(acc[mt][0][r] + bi);
          float gv = tanhf_fast(acc[mt][1][r] + bg);
          float fv = sigf(acc[mt][2][r] + bf);
          float ov = sigf(acc[mt][3][r] + bo);
          float ct = fv * c[mt][r] + iv * gv;
          c[mt][r] = ct;
          const int m = wv * 32 + mt * 16 + quad * 4 + r;
          store_h(hw + (size_t)m * HH + u, ov * tanhf_fast(ct));
        }
      stepbar(lbar, gbar, lcnt, nldr, leader, (unsigned)t);
    }
  } else {
    // fc block: y_{t-1} = h_{t-1} @ W_fc^T + b_fc, overlapped with step-t gate GEMMs
    const int fb = bid - NGB;
    const int pcol = fb * 16 + l15;
    const float biasf = b_fc[pcol];
    const int abase0 = ((wv * 2 + 0) * 16 + l15) * 128 + quad;
    const int abase1 = ((wv * 2 + 1) * 16 + l15) * 128 + quad;

    gridbar_flat(fbar, NB);   // t = 0: nothing to project yet; also publishes census

    unsigned lcnt = 0, nldr = 0; unsigned* lbar = nullptr; bool leader = false;
    if (tid == 0) {
      lcnt = __hip_atomic_load(&census[myx], __ATOMIC_RELAXED, __HIP_MEMORY_SCOPE_AGENT);
      for (int i = 0; i < 8; ++i)
        nldr += (__hip_atomic_load(&census[i], __ATOMIC_RELAXED, __HIP_MEMORY_SCOPE_AGENT) > 0);
      lbar = ctl + 128 + myx * 32;
      leader = (rank == 0);
    }

    for (int t = 1; t <= TT; ++t) {
      const half8* hb8 = (const half8*)(hbuf + (size_t)((t - 1) & 1) * BB * HH);
      floatx4 acc[2][1] = {{z4}, {z4}};
      gemm2xNT<1>(hb8, w8, abase0, abase1, quad, rsw, l15, acc);
#pragma unroll
      for (int mt = 0; mt < 2; ++mt)
#pragma unroll
        for (int r = 0; r < 4; ++r) {
          const int m = (wv * 2 + mt) * 16 + quad * 4 + r;
          out[(size_t)m * (TT * PP) + (size_t)(t - 1) * PP + pcol] = acc[mt][0][r] + biasf;
        }
      if (t < TT) stepbar(lbar, gbar, lcnt, nldr, leader, (unsigned)t);
    }
  }
}

extern "C" void kernel_launch(void* const* d_in, const int* in_sizes, int n_in,
                              void* d_out, int out_size, void* d_ws, size_t ws_size,
                              hipStream_t stream) {
  const float* z    = (const float*)d_in[1];
  const float* w_ih = (const float*)d_in[2];
  const float* w_hh = (const float*)d_in[3];
  const float* b_ih = (const float*)d_in[4];
  const float* b_hh = (const float*)d_in[5];
  const float* W_fc = (const float*)d_in[6];
  const float* b_fc = (const float*)d_in[7];
  float* out = (float*)d_out;

  // workspace layout (~10.8 MiB total)
  char* ws = (char*)d_ws;
  unsigned*       ctl  = (unsigned*)ws;                                        // 4 KiB ctrl
  unsigned short* hbuf = (unsigned short*)(ws + 4096);                         // 512 KiB
  float*          g0   = (float*)(ws + 4096 + (size_t)2 * BB * HH * 2);        // 2 MiB
  unsigned short* wbuf = (unsigned short*)(ws + 4096 + (size_t)2 * BB * HH * 2
                                              + (size_t)BB * G4 * 4);          // 8.25 MiB

  // allow 128 KiB dynamic LDS (gfx950 has 160 KiB/CU)
  (void)hipFuncSetAttribute(reinterpret_cast<const void*>(lstm_persist),
                            hipFuncAttributeMaxDynamicSharedMemorySize, 160 * 1024);

  hipMemsetAsync(ctl, 0, 4096, stream);
  prep_gates0 <<<dim3(G4), dim3(BB), 0, stream>>>(z, w_ih, b_ih, b_hh, g0);
  prep_weights<<<dim3(NGB * 64 + NFB * 16), dim3(256), 0, stream>>>(w_hh, W_fc, wbuf);
  lstm_persist<<<dim3(NB), dim3(256), 128 * 1024, stream>>>(g0, wbuf, b_ih, b_hh, b_fc,
                                                            out, hbuf, ctl);
}